// Round 8
// baseline (295.491 us; speedup 1.0000x reference)
//
#include <hip/hip_runtime.h>
#include <hip/hip_bf16.h>

#define N_NODES 100000
#define N_EDGES 3200000
#define D 128

typedef unsigned short u16;

// sort parameters (round-8: 500 buckets x 200 nodes = 100000 exactly;
// one bucket = one agg_fused block -> 500 blocks fills 256 CUs)
#define BKT_W 200                 // dst nodes per bucket
#define NBKT 500                  // 100000/200
#define NSH 8                     // shards per bucket
#define CAPS 960                  // capacity per (bucket,shard); mean ~809, +5.3 sigma
#define SLW (NSH * CAPS)          // 7680 words per bucket region
#define EPB 5120                  // edges per pass-1 block
#define P1B 625                   // pass-1 blocks (625*5120 = 3.2M exactly)
#define EPT 20                    // edges per thread (5120/256)
#define GEMM_B 1563               // gemm tail blocks on p1 grid: ceil(100000/64)

typedef __attribute__((ext_vector_type(8))) short bf16x8;
typedef __attribute__((ext_vector_type(4))) float f32x4;

__device__ __forceinline__ float asf(unsigned u) {
    union { unsigned i; float f; } a; a.i = u; return a.f;
}
__device__ __forceinline__ u16 f2bf(float f) {
    __hip_bfloat16 b = __float2bfloat16(f);
    return *(u16*)&b;
}

// ---- W -> bf16 (tiny, runs first so fused gemm blocks can read wbf) ----
__global__ __launch_bounds__(256) void wconv(const float* __restrict__ w,
                                             u16* __restrict__ wbf) {
    int idx = blockIdx.x * 256 + threadIdx.x;   // 0..2047
    const float4* wp = (const float4*)(w + (size_t)idx * 8);
    float4 a = wp[0], bb = wp[1];
    union { u16 h[8]; uint4 v; } o;
    o.h[0] = f2bf(a.x); o.h[1] = f2bf(a.y);
    o.h[2] = f2bf(a.z); o.h[3] = f2bf(a.w);
    o.h[4] = f2bf(bb.x); o.h[5] = f2bf(bb.y);
    o.h[6] = f2bf(bb.z); o.h[7] = f2bf(bb.w);
    ((uint4*)wbf)[idx] = o.v;
}

// ---- p1 (blocks [0,P1B)): LDS multisplit into 500 buckets, sharded append.
//      Tail blocks: h[n] = bf16(x[n] @ W^T) (no dinv; applied at aggregate). ----
__global__ __launch_bounds__(256) void p1_gemm(const int* __restrict__ ei,
                                               int* __restrict__ bcnt,
                                               unsigned* __restrict__ bbuf,
                                               const float* __restrict__ x,
                                               const u16* __restrict__ wbf,
                                               u16* __restrict__ h) {
    __shared__ unsigned s1[EPB];
    __shared__ unsigned s2[EPB];
    __shared__ int hist[NBKT], lbase[NBKT], cur[NBKT], gbase[NBKT];
    __shared__ int wsum4[4], wbase4[4];
    int t = threadIdx.x, blk = blockIdx.x;

    if (blk >= P1B) {
        // ---------------- GEMM tail (round-1 verified MFMA layout) ----------------
        int wave = t >> 6, lane = t & 63;
        int n0 = (blk - P1B) * 64 + wave * 16;
        int lrow = lane & 15;
        int quad = lane >> 4;

        int arow = n0 + lrow;
        const float* ap = x + (size_t)(arow < N_NODES ? arow : 0) * D;
        bf16x8 afrag[4];
#pragma unroll
        for (int kt = 0; kt < 4; ++kt) {
            int k0 = kt * 32 + quad * 8;
            f32x4 x0 = *(const f32x4*)(ap + k0);
            f32x4 x1 = *(const f32x4*)(ap + k0 + 4);
            bf16x8 a;
            a[0] = (short)f2bf(x0.x); a[1] = (short)f2bf(x0.y);
            a[2] = (short)f2bf(x0.z); a[3] = (short)f2bf(x0.w);
            a[4] = (short)f2bf(x1.x); a[5] = (short)f2bf(x1.y);
            a[6] = (short)f2bf(x1.z); a[7] = (short)f2bf(x1.w);
            afrag[kt] = a;
        }

#pragma unroll
        for (int jt = 0; jt < 8; ++jt) {
            int j0 = jt * 16;
            f32x4 acc = {0.f, 0.f, 0.f, 0.f};
#pragma unroll
            for (int kt = 0; kt < 4; ++kt) {
                int k0 = kt * 32 + quad * 8;
                bf16x8 b = *(const bf16x8*)(wbf + (size_t)(j0 + lrow) * D + k0);
                acc = __builtin_amdgcn_mfma_f32_16x16x32_bf16(afrag[kt], b, acc, 0, 0, 0);
            }
#pragma unroll
            for (int i = 0; i < 4; ++i) {
                int n = n0 + quad * 4 + i;
                if (n < N_NODES) h[(size_t)n * D + j0 + lrow] = f2bf(acc[i]);
            }
        }
        return;
    }

    // ---------------- p1 multisplit ----------------
    int sh = blk & (NSH - 1);
    int e0 = blk * EPB;
    for (int i = t; i < NBKT; i += 256) hist[i] = 0;
    __syncthreads();

    unsigned short bk[EPT];
#pragma unroll
    for (int k = 0; k < 5; ++k) {
        int base = k * 1024 + t * 4;          // 4 consecutive edges
        int4 s4 = *(const int4*)(ei + e0 + base);
        int4 d4 = *(const int4*)(ei + N_EDGES + e0 + base);
        int ss[4] = {s4.x, s4.y, s4.z, s4.w};
        int dd[4] = {d4.x, d4.y, d4.z, d4.w};
#pragma unroll
        for (int j = 0; j < 4; ++j) {
            unsigned bkt = (unsigned)dd[j] / BKT_W;   // magic-mul
            unsigned dl = (unsigned)dd[j] - bkt * BKT_W;
            bk[k * 4 + j] = (unsigned short)bkt;
            s1[base + j] = ((unsigned)ss[j] << 9) | dl;
            atomicAdd(&hist[bkt], 1);
        }
    }
    __syncthreads();

    for (int i = t; i < NBKT; i += 256)
        gbase[i] = atomicAdd(&bcnt[i * NSH + sh], hist[i]);

    // exclusive prefix over hist[0..499]: pair trick (250 pairs) + wave scan
    int lane = t & 63, wv = t >> 6;
    int a0 = 0, a1 = 0, v = 0;
    if (t < 250) { a0 = hist[2 * t]; a1 = hist[2 * t + 1]; v = a0 + a1; }
    int pre = v;
#pragma unroll
    for (int o = 1; o < 64; o <<= 1) {
        int u = __shfl_up(pre, o);
        if (lane >= o) pre += u;
    }
    if (lane == 63) wsum4[wv] = pre;
    __syncthreads();
    if (t == 0) {
        int b = 0;
#pragma unroll
        for (int k = 0; k < 4; ++k) { wbase4[k] = b; b += wsum4[k]; }
    }
    __syncthreads();
    if (t < 250) {
        int ex = wbase4[wv] + pre - v;
        lbase[2 * t] = ex;        cur[2 * t] = ex;
        lbase[2 * t + 1] = ex + a0; cur[2 * t + 1] = ex + a0;
    }
    __syncthreads();

#pragma unroll
    for (int k = 0; k < 5; ++k) {
        int base = k * 1024 + t * 4;
#pragma unroll
        for (int j = 0; j < 4; ++j) {
            int p = atomicAdd(&cur[bk[k * 4 + j]], 1);
            s2[p] = s1[base + j];
        }
    }
    __syncthreads();

    for (int bkt = wv; bkt < NBKT; bkt += 4) {
        int n = hist[bkt], lb = lbase[bkt], gb = gbase[bkt];
        unsigned* dst = bbuf + ((size_t)bkt * NSH + sh) * CAPS;
        for (int j = lane; j < n; j += 64) {
            int p = gb + j;
            if (p < CAPS) dst[p] = s2[lb + j];
        }
    }
}

// ---- p2_deg: per-bucket hist only -> cnt, beg (LOCAL offset), dinv.
//      No staging, no placement, no sorted write (placement lives in agg_fused;
//      dinv must exist globally before any gather of dinv[src]). ----
__global__ __launch_bounds__(256) void p2_deg(const unsigned* __restrict__ bbuf,
                                              const int* __restrict__ bcnt,
                                              int* __restrict__ cnt_g,
                                              int* __restrict__ begl_g,
                                              float* __restrict__ dinv_g) {
    __shared__ int hist[BKT_W];
    __shared__ int shcnt[NSH];
    __shared__ int wsum4[4], wbase4[4];
    int b = blockIdx.x, t = threadIdx.x;

    if (t < NSH) { int m = bcnt[b * NSH + t]; shcnt[t] = m > CAPS ? CAPS : m; }
    if (t < BKT_W) hist[t] = 0;
    __syncthreads();

    const unsigned* bb = bbuf + (size_t)b * SLW;
    for (int i = t; i < SLW; i += 256) {
        int shd = i / CAPS;               // magic-mul
        int off = i - shd * CAPS;
        if (off < shcnt[shd]) atomicAdd(&hist[bb[i] & 511u], 1);
    }
    __syncthreads();

    // exclusive prefix over hist[0..199] via wave scan + wsum combine
    int lane = t & 63, wv = t >> 6;
    int hv = (t < BKT_W) ? hist[t] : 0;
    int pre = hv;
#pragma unroll
    for (int o = 1; o < 64; o <<= 1) {
        int u = __shfl_up(pre, o);
        if (lane >= o) pre += u;
    }
    if (lane == 63) wsum4[wv] = pre;
    __syncthreads();
    if (t == 0) {
        int bb2 = 0;
#pragma unroll
        for (int k = 0; k < 4; ++k) { wbase4[k] = bb2; bb2 += wsum4[k]; }
    }
    __syncthreads();
    if (t < BKT_W) {
        int node = b * BKT_W + t;
        cnt_g[node] = hv;
        begl_g[node] = wbase4[wv] + pre - hv;   // offset within bucket
        dinv_g[node] = rsqrtf((float)(hv + 1));
    }
}

// ---- agg_fused: block = bucket. Phase A: place bucket edges into LDS sorted
//      list (p2's proven counting-sort placement, 1 LDS atomic per edge).
//      Phase B: round-7 proven gather loop, indices read from LDS; node queue
//      via LDS atomic balances waves.
//      out[n] = dinv[n]*(dinv[n]*h[n] + sum_s dinv[s]*h[s]) + bias. ----
__global__ __launch_bounds__(1024) void agg_fused(const u16* __restrict__ h,
                                                  const float* __restrict__ dinv,
                                                  const int* __restrict__ cnt_g,
                                                  const int* __restrict__ begl_g,
                                                  const int* __restrict__ bcnt,
                                                  const unsigned* __restrict__ bbuf,
                                                  const float* __restrict__ bias,
                                                  float* __restrict__ out) {
    __shared__ int sl[SLW];               // 30.7 KB sorted src list
    __shared__ int cur[BKT_W], begs[BKT_W];
    __shared__ int shcnt[NSH];
    __shared__ int nctr;
    int b = blockIdx.x, t = threadIdx.x;

    if (t < NSH) { int m = bcnt[b * NSH + t]; shcnt[t] = m > CAPS ? CAPS : m; }
    if (t < BKT_W) { int e = begl_g[b * BKT_W + t]; cur[t] = e; begs[t] = e; }
    if (t == 0) nctr = 0;
    __syncthreads();

    // Phase A: placement (coalesced bbuf read, 1 LDS atomic + 1 LDS write per edge)
    const unsigned* bb = bbuf + (size_t)b * SLW;
    for (int i = t; i < SLW; i += 1024) {
        int shd = i / CAPS;               // magic-mul
        int off = i - shd * CAPS;
        if (off < shcnt[shd]) {
            unsigned w = bb[i];
            int pp = atomicAdd(&cur[w & 511u], 1);
            sl[pp] = (int)(w >> 9);
        }
    }
    __syncthreads();

    // Phase B: gather-aggregate (proven 16/4/1 batch structure)
    const unsigned* h32 = (const unsigned*)h;
    int l = t & 63;
    float2 bs = ((const float2*)bias)[l];

    while (true) {
        int nl0 = 0;
        if (l == 0) nl0 = atomicAdd(&nctr, 1);
        int nl = __shfl(nl0, 0);
        if (nl >= BKT_W) break;
        int n = b * BKT_W + nl;

        float dn = dinv[n];
        unsigned us = h32[(size_t)n * 64 + l];   // self-loop: dinv[n]*h[n]
        float acc0 = dn * asf(us << 16);
        float acc1 = dn * asf(us & 0xffff0000u);

        int cn = __builtin_amdgcn_readfirstlane(cnt_g[n]);
        int lb = __builtin_amdgcn_readfirstlane(begs[nl]);

        int i = 0;
        for (; i + 16 <= cn; i += 16) {
            int s[16];
#pragma unroll
            for (int j = 0; j < 16; ++j)
                s[j] = __builtin_amdgcn_readfirstlane(sl[lb + i + j]);
            float dv[16];
#pragma unroll
            for (int j = 0; j < 16; ++j) dv[j] = dinv[s[j]];
            unsigned u[16];
#pragma unroll
            for (int j = 0; j < 16; ++j) u[j] = h32[(size_t)s[j] * 64 + l];
#pragma unroll
            for (int j = 0; j < 16; ++j) {
                acc0 += dv[j] * asf(u[j] << 16);
                acc1 += dv[j] * asf(u[j] & 0xffff0000u);
            }
        }
        for (; i + 4 <= cn; i += 4) {
            int s0 = __builtin_amdgcn_readfirstlane(sl[lb + i]);
            int s1 = __builtin_amdgcn_readfirstlane(sl[lb + i + 1]);
            int s2 = __builtin_amdgcn_readfirstlane(sl[lb + i + 2]);
            int s3 = __builtin_amdgcn_readfirstlane(sl[lb + i + 3]);
            float d0 = dinv[s0], d1 = dinv[s1], d2 = dinv[s2], d3 = dinv[s3];
            unsigned u0 = h32[(size_t)s0 * 64 + l];
            unsigned u1 = h32[(size_t)s1 * 64 + l];
            unsigned u2 = h32[(size_t)s2 * 64 + l];
            unsigned u3 = h32[(size_t)s3 * 64 + l];
            acc0 += d0 * asf(u0 << 16); acc1 += d0 * asf(u0 & 0xffff0000u);
            acc0 += d1 * asf(u1 << 16); acc1 += d1 * asf(u1 & 0xffff0000u);
            acc0 += d2 * asf(u2 << 16); acc1 += d2 * asf(u2 & 0xffff0000u);
            acc0 += d3 * asf(u3 << 16); acc1 += d3 * asf(u3 & 0xffff0000u);
        }
        for (; i < cn; ++i) {
            int s = __builtin_amdgcn_readfirstlane(sl[lb + i]);
            float dv = dinv[s];
            unsigned u = h32[(size_t)s * 64 + l];
            acc0 += dv * asf(u << 16); acc1 += dv * asf(u & 0xffff0000u);
        }

        float2 o;
        o.x = acc0 * dn + bs.x;
        o.y = acc1 * dn + bs.y;
        ((float2*)out)[(size_t)n * 64 + l] = o;
    }
    if (b == 0 && t == 0) out[(size_t)N_NODES * D] = 0.f;  // tuple scalar
}

extern "C" void kernel_launch(void* const* d_in, const int* in_sizes, int n_in,
                              void* d_out, int out_size, void* d_ws, size_t ws_size,
                              hipStream_t stream) {
    const float* x = (const float*)d_in[0];
    const int* ei = (const int*)d_in[1];
    const float* w = (const float*)d_in[2];
    const float* bias = (const float*)d_in[3];
    float* out = (float*)d_out;

    char* ws = (char*)d_ws;
    size_t o = 0;
    auto alloc = [&](size_t bytes) -> char* {
        char* p = ws + o;
        o = (o + bytes + 511) & ~(size_t)511;
        return p;
    };
    u16* h = (u16*)alloc((size_t)N_NODES * D * 2);              // 25.6 MB
    unsigned* bbuf = (unsigned*)alloc((size_t)NBKT * SLW * 4);  // 15.36 MB
    int* cnt = (int*)alloc((size_t)N_NODES * 4);                // 0.4 MB
    int* begl = (int*)alloc((size_t)N_NODES * 4);               // 0.4 MB
    float* dinv = (float*)alloc((size_t)N_NODES * 4);           // 0.4 MB
    int* bcnt = (int*)alloc((size_t)NBKT * NSH * 4);            // 16 KB
    u16* wbf = (u16*)alloc((size_t)D * D * 2);                  // 32 KB
    // total ws: ~42.2 MB

    hipMemsetAsync(bcnt, 0, (size_t)NBKT * NSH * 4, stream);

    wconv<<<8, 256, 0, stream>>>(w, wbf);
    p1_gemm<<<P1B + GEMM_B, 256, 0, stream>>>(ei, bcnt, bbuf, x, wbf, h);
    p2_deg<<<NBKT, 256, 0, stream>>>(bbuf, bcnt, cnt, begl, dinv);
    agg_fused<<<NBKT, 1024, 0, stream>>>(h, dinv, cnt, begl, bcnt, bbuf, bias, out);
}